// Round 2
// baseline (29433.740 us; speedup 1.0000x reference)
//
#include <hip/hip_runtime.h>
#include <hip/hip_fp16.h>

#define SEQL 4096
#define EMBD 512
#define HIDD 2048
#define NCH  256
#define WCOL 2560   // EMB + HID

typedef _Float16 half8_t __attribute__((ext_vector_type(8)));
typedef _Float16 half2_t __attribute__((ext_vector_type(2)));
typedef float    float4_t __attribute__((ext_vector_type(4)));

#if __has_builtin(__builtin_amdgcn_fdot2)
__device__ __forceinline__ float fdot2u(unsigned a, unsigned b, float c) {
  return __builtin_amdgcn_fdot2(__builtin_bit_cast(half2_t, a),
                                __builtin_bit_cast(half2_t, b), c, false);
}
#else
__device__ __forceinline__ float fdot2u(unsigned a, unsigned b, float c) {
  half2_t ha = __builtin_bit_cast(half2_t, a), hb = __builtin_bit_cast(half2_t, b);
  return c + (float)ha.x * (float)hb.x + (float)ha.y * (float)hb.y;
}
#endif

__device__ __forceinline__ float sigm_f(float x)  { return 1.f / (1.f + __expf(-x)); }
__device__ __forceinline__ float tanh_f(float x)  { return 1.f - 2.f / (__expf(2.f * x) + 1.f); }

// ---------------------------------------------------------------------------
// prep: f32->f16 conversions (emb gather, stacked recurrent-GEMM B, Wy) and
//       zeroing of the h-exchange record buffer (must re-run every launch).
// ---------------------------------------------------------------------------
__global__ void prep_kernel(const int* __restrict__ seq, const float* __restrict__ emb,
                            const float* __restrict__ Wf, const float* __restrict__ Wi,
                            const float* __restrict__ Wo, const float* __restrict__ Wc,
                            const float* __restrict__ Wy,
                            _Float16* __restrict__ emb16, _Float16* __restrict__ Wst16,
                            _Float16* __restrict__ Wy16, unsigned* __restrict__ hx)
{
  const long nEmb = (long)SEQL * EMBD;       // 2M
  const long nWst = (long)4 * HIDD * EMBD;   // 4M
  const long nWy  = (long)NCH * HIDD;        // 512K
  const long nHx  = 2 * 256 * 32;            // 16K dwords = 64 KB record area
  const long total = nEmb + nWst + nWy + nHx;
  long stride = (long)gridDim.x * blockDim.x;
  for (long i = (long)blockIdx.x * blockDim.x + threadIdx.x; i < total; i += stride) {
    if (i < nEmb) {
      long t = i >> 9, e = i & 511;
      emb16[i] = (_Float16)emb[(long)seq[t] * EMBD + e];
    } else if (i < nEmb + nWst) {
      long j = i - nEmb;
      long row = j >> 9, k = j & 511;
      long r = row >> 11, jr = row & 2047;
      const float* W = (r == 0) ? Wf : (r == 1) ? Wi : (r == 2) ? Wo : Wc;
      Wst16[j] = (_Float16)W[jr * WCOL + k];
    } else if (i < nEmb + nWst + nWy) {
      long j = i - nEmb - nWst;
      Wy16[j] = (_Float16)Wy[j];             // Wy is row-major 256x2048, 1:1 copy
    } else {
      hx[i - nEmb - nWst - nWy] = 0u;
    }
  }
}

// ---------------------------------------------------------------------------
// gemm_bt: C[M][N] = A[M][K] * B[N][K]^T   (both K-contiguous f16, MFMA 16x16x32)
// MODE 0: store f16 to C16 (ldc=N).  MODE 1: store f32 + bias to Cf (ldc=N).
// 128x128 tile, BK=32, 256 threads (4 waves as 2x2 of 64x64).
// ---------------------------------------------------------------------------
template<int K, int MODE>
__global__ __launch_bounds__(256) void gemm_bt(const _Float16* __restrict__ A,
                                               const _Float16* __restrict__ B,
                                               _Float16* __restrict__ C16,
                                               float* __restrict__ Cf,
                                               const float* __restrict__ bias, int N)
{
  __shared__ _Float16 At[128 * 32];
  __shared__ _Float16 Bt[128 * 32];
  const int tid = threadIdx.x;
  const int w = tid >> 6, lane = tid & 63;
  const int wm = w >> 1, wn = w & 1;
  const int lr = lane & 15, kg = lane >> 4;
  const long tm = (long)blockIdx.y * 128;
  const long tn = (long)blockIdx.x * 128;

  float4_t acc[4][4];
#pragma unroll
  for (int a = 0; a < 4; a++)
#pragma unroll
    for (int b = 0; b < 4; b++) acc[a][b] = (float4_t)0.f;

  for (int kt = 0; kt < K; kt += 32) {
    __syncthreads();
#pragma unroll
    for (int s = 0; s < 2; s++) {
      int l = s * 256 + tid;
      int row = l >> 2, ks = (l & 3) * 8;
      *(uint4*)&At[row * 32 + ks] = *(const uint4*)&A[(tm + row) * (long)K + kt + ks];
      *(uint4*)&Bt[row * 32 + ks] = *(const uint4*)&B[(tn + row) * (long)K + kt + ks];
    }
    __syncthreads();
    half8_t af[4], bf[4];
#pragma unroll
    for (int mi = 0; mi < 4; mi++) af[mi] = *(const half8_t*)&At[(wm * 64 + mi * 16 + lr) * 32 + kg * 8];
#pragma unroll
    for (int ni = 0; ni < 4; ni++) bf[ni] = *(const half8_t*)&Bt[(wn * 64 + ni * 16 + lr) * 32 + kg * 8];
#pragma unroll
    for (int mi = 0; mi < 4; mi++)
#pragma unroll
      for (int ni = 0; ni < 4; ni++)
        acc[mi][ni] = __builtin_amdgcn_mfma_f32_16x16x32_f16(af[mi], bf[ni], acc[mi][ni], 0, 0, 0);
  }

#pragma unroll
  for (int mi = 0; mi < 4; mi++)
#pragma unroll
    for (int ni = 0; ni < 4; ni++)
#pragma unroll
      for (int i = 0; i < 4; i++) {
        long gm = tm + wm * 64 + mi * 16 + kg * 4 + i;
        long gn = tn + wn * 64 + ni * 16 + lr;
        float v = acc[mi][ni][i];
        if (MODE == 0) C16[gm * (long)N + gn] = (_Float16)v;
        else           Cf[gm * (long)N + gn] = v + bias[gn];
      }
}

// ---------------------------------------------------------------------------
// lstm_seq: persistent scan. 256 WGs x 512 threads. WG g owns hidden units
// g*8..g*8+7 (all 4 gates = 32 rows of stacked Whh, f16 in VGPRs: 64 regs/lane).
// Wave layout: wave w has rows 4w..4w+3; 16 lanes per row (hsub=lane&15).
// Lane's k slice: k = it*64 + hsub*4 + {0..3}, it = 0..31.
//
// h exchange (R2): per-producer 128 B record per parity:
//   rec[parity][g] = { dword0..3: 8 x f16 h values, dword4: tag (=t+1), pad }
// Producer: 8 lanes store ushort h (one instr) -> lane0 RELEASE-stores tag
// (the release's wave-level vmcnt(0) orders the data ahead of the tag; any
// cache-line snapshot with the new tag therefore has the new data).
// Consumer: threads 0..255 poll one tag each (relaxed, s_sleep backoff), then
// read the 16 B data (same line, L2-hit) and distribute via LDS.
// ---------------------------------------------------------------------------
__global__ __launch_bounds__(512) void lstm_seq(
    const _Float16* __restrict__ xq,   // [SEQ][4*HID] gate-major
    const float* __restrict__ Wf, const float* __restrict__ Wi,
    const float* __restrict__ Wo, const float* __restrict__ Wc,
    const float* __restrict__ bfp, const float* __restrict__ bip,
    const float* __restrict__ bop, const float* __restrict__ bcp,
    unsigned* __restrict__ hx,         // [2][256][32] dwords (128B records)
    _Float16* __restrict__ H16,        // [SEQ][HID]
    float* __restrict__ out)
{
  __shared__ unsigned hbuf[HIDD / 2];  // f16 pairs of h_{t-1}
  __shared__ float gl[32];             // activated gates for this WG

  const int tid  = threadIdx.x;
  const int wave = tid >> 6, lane = tid & 63;
  const int rw   = lane >> 4, hsub = lane & 15;
  const int row_local = wave * 4 + rw;       // 0..31
  const int r  = row_local >> 3;             // gate: 0=f 1=i 2=o 3=c
  const int jj = row_local & 7;
  const int g  = blockIdx.x;
  const int jg = g * 8 + jj;

  const float* Wsel = (r == 0) ? Wf : (r == 1) ? Wi : (r == 2) ? Wo : Wc;
  const float* bsel = (r == 0) ? bfp : (r == 1) ? bip : (r == 2) ? bop : bcp;
  const float* wrow = Wsel + (long)jg * WCOL + EMBD;

  uint2 wreg[32];
#pragma unroll
  for (int it = 0; it < 32; ++it) {
    const float4 wv = *(const float4*)(wrow + it * 64 + hsub * 4);
    half2_t lo = { (_Float16)wv.x, (_Float16)wv.y };
    half2_t hi = { (_Float16)wv.z, (_Float16)wv.w };
    wreg[it].x = __builtin_bit_cast(unsigned, lo);
    wreg[it].y = __builtin_bit_cast(unsigned, hi);
  }
  const float bias = (hsub == 0) ? bsel[jg] : 0.f;

  float c = 0.f;   // cell state lives in wave-0 lanes 0..7

  for (int t = 0; t < SEQL; ++t) {
    // x prefetch (leaders only) — independent of h, issues before the poll
    float xv = 0.f;
    if (hsub == 0) xv = (float)xq[(long)t * 8192 + r * HIDD + g * 8 + jj];

    if (t == 0) {
      if (tid < 256) {
        hbuf[tid * 4 + 0] = 0u; hbuf[tid * 4 + 1] = 0u;
        hbuf[tid * 4 + 2] = 0u; hbuf[tid * 4 + 3] = 0u;   // h_{-1} = 0
      }
    } else if (tid < 256) {
      unsigned* rec = hx + (long)(t & 1) * 8192 + tid * 32;
      const unsigned tg = (unsigned)t;
      int guard = 0;
      for (;;) {
        unsigned v = __hip_atomic_load(rec + 4, __ATOMIC_RELAXED, __HIP_MEMORY_SCOPE_AGENT);
        if (v == tg) break;
        __builtin_amdgcn_s_sleep(1);
        if (++guard > (1 << 20)) break;   // emergency escape (never in normal flow)
      }
      unsigned d0 = __hip_atomic_load(rec + 0, __ATOMIC_RELAXED, __HIP_MEMORY_SCOPE_AGENT);
      unsigned d1 = __hip_atomic_load(rec + 1, __ATOMIC_RELAXED, __HIP_MEMORY_SCOPE_AGENT);
      unsigned d2 = __hip_atomic_load(rec + 2, __ATOMIC_RELAXED, __HIP_MEMORY_SCOPE_AGENT);
      unsigned d3 = __hip_atomic_load(rec + 3, __ATOMIC_RELAXED, __HIP_MEMORY_SCOPE_AGENT);
      hbuf[tid * 4 + 0] = d0; hbuf[tid * 4 + 1] = d1;
      hbuf[tid * 4 + 2] = d2; hbuf[tid * 4 + 3] = d3;
    }
    __syncthreads();

    // matvec: row dot h over this lane's k slice
    float a0 = 0.f, a1 = 0.f, a2 = 0.f, a3 = 0.f;
#pragma unroll
    for (int it = 0; it < 32; ++it) {
      const uint2 hv = *(const uint2*)&hbuf[it * 32 + hsub * 2];
      if (it & 1) { a2 = fdot2u(wreg[it].x, hv.x, a2); a3 = fdot2u(wreg[it].y, hv.y, a3); }
      else        { a0 = fdot2u(wreg[it].x, hv.x, a0); a1 = fdot2u(wreg[it].y, hv.y, a1); }
    }
    float s = (a0 + a1) + (a2 + a3);
    s += __shfl_xor(s, 1, 64);
    s += __shfl_xor(s, 2, 64);
    s += __shfl_xor(s, 4, 64);
    s += __shfl_xor(s, 8, 64);

    if (hsub == 0) {
      const float pre = s + xv + bias;
      gl[row_local] = (r == 3) ? tanh_f(pre) : sigm_f(pre);
    }
    __syncthreads();

    if (tid < 8) {
      const float f  = gl[tid];
      const float ii = gl[8 + tid];
      const float o  = gl[16 + tid];
      const float cg = gl[24 + tid];
      c = f * c + ii * cg;
      const float h = o * tanh_f(c);
      const _Float16 hh = (_Float16)h;
      // exchange record for step t+1 (parity (t+1)&1): data first...
      unsigned* recn = hx + (long)((t + 1) & 1) * 8192 + g * 32;
      __hip_atomic_store((unsigned short*)recn + tid,
                         __builtin_bit_cast(unsigned short, hh),
                         __ATOMIC_RELAXED, __HIP_MEMORY_SCOPE_AGENT);
      // ...then tag with release (wave-level vmcnt covers the 8-lane data store)
      if (tid == 0)
        __hip_atomic_store(recn + 4, (unsigned)(t + 1),
                           __ATOMIC_RELEASE, __HIP_MEMORY_SCOPE_AGENT);
      H16[(long)t * HIDD + g * 8 + tid] = hh;
      if (t == SEQL - 1) {
        out[(long)SEQL * NCH + g * 8 + tid] = h;                 // final h
        out[(long)SEQL * NCH + HIDD + g * 8 + tid] = c;          // final c
      }
    }
  }
}

// ---------------------------------------------------------------------------
extern "C" void kernel_launch(void* const* d_in, const int* in_sizes, int n_in,
                              void* d_out, int out_size, void* d_ws, size_t ws_size,
                              hipStream_t stream) {
  const int*   seq = (const int*)d_in[0];
  const float* emb = (const float*)d_in[1];
  const float* Wf  = (const float*)d_in[2];
  const float* bf_ = (const float*)d_in[3];
  const float* Wi  = (const float*)d_in[4];
  const float* bi_ = (const float*)d_in[5];
  const float* Wo  = (const float*)d_in[6];
  const float* bo_ = (const float*)d_in[7];
  const float* Wc  = (const float*)d_in[8];
  const float* bc_ = (const float*)d_in[9];
  const float* Wy  = (const float*)d_in[10];
  const float* by  = (const float*)d_in[11];
  float* out = (float*)d_out;

  char* ws = (char*)d_ws;
  _Float16* xq     = (_Float16*)(ws);                          // 64 MB: [4096][8192]
  _Float16* emb16  = (_Float16*)(ws + (64ll << 20));           //  4 MB: [4096][512]
  _Float16* Wst16  = (_Float16*)(ws + (68ll << 20));           //  8 MB: [8192][512]
  _Float16* Wy16   = (_Float16*)(ws + (76ll << 20));           //  1 MB: [256][2048]
  _Float16* H16    = (_Float16*)(ws + (77ll << 20));           // 16 MB: [4096][2048]
  unsigned* hx     = (unsigned*)(ws + (93ll << 20));           // 64 KB: [2][256][32] dwords

  prep_kernel<<<2048, 256, 0, stream>>>(seq, emb, Wf, Wi, Wo, Wc, Wy,
                                        emb16, Wst16, Wy16, hx);

  dim3 g1(8192 / 128, 4096 / 128);   // N tiles x M tiles
  gemm_bt<EMBD, 0><<<g1, 256, 0, stream>>>(emb16, Wst16, xq, nullptr, nullptr, 8192);

  lstm_seq<<<256, 512, 0, stream>>>(xq, Wf, Wi, Wo, Wc, bf_, bi_, bo_, bc_,
                                    hx, H16, out);

  dim3 g2(NCH / 128, 4096 / 128);
  gemm_bt<HIDD, 1><<<g2, 256, 0, stream>>>(H16, Wy16, nullptr, out, by, NCH);
}

// Round 3
// 15484.654 us; speedup vs baseline: 1.9008x; 1.9008x over previous
//
#include <hip/hip_runtime.h>
#include <hip/hip_fp16.h>

#define SEQL 4096
#define EMBD 512
#define HIDD 2048
#define NCH  256
#define WCOL 2560   // EMB + HID

typedef _Float16 half8_t __attribute__((ext_vector_type(8)));
typedef _Float16 half2_t __attribute__((ext_vector_type(2)));
typedef float    float4_t __attribute__((ext_vector_type(4)));

#if __has_builtin(__builtin_amdgcn_fdot2)
__device__ __forceinline__ float fdot2u(unsigned a, unsigned b, float c) {
  return __builtin_amdgcn_fdot2(__builtin_bit_cast(half2_t, a),
                                __builtin_bit_cast(half2_t, b), c, false);
}
#else
__device__ __forceinline__ float fdot2u(unsigned a, unsigned b, float c) {
  half2_t ha = __builtin_bit_cast(half2_t, a), hb = __builtin_bit_cast(half2_t, b);
  return c + (float)ha.x * (float)hb.x + (float)ha.y * (float)hb.y;
}
#endif

__device__ __forceinline__ float sigm_f(float x)  { return 1.f / (1.f + __expf(-x)); }
__device__ __forceinline__ float tanh_f(float x)  { return 1.f - 2.f / (__expf(2.f * x) + 1.f); }

// ---------------------------------------------------------------------------
// prep: f32->f16 conversions (emb gather, stacked recurrent-GEMM B, Wy) and
//       zeroing of the h-exchange record buffer (must re-run every launch:
//       stale tags from a previous replay would falsely match).
// ---------------------------------------------------------------------------
__global__ void prep_kernel(const int* __restrict__ seq, const float* __restrict__ emb,
                            const float* __restrict__ Wf, const float* __restrict__ Wi,
                            const float* __restrict__ Wo, const float* __restrict__ Wc,
                            const float* __restrict__ Wy,
                            _Float16* __restrict__ emb16, _Float16* __restrict__ Wst16,
                            _Float16* __restrict__ Wy16, unsigned* __restrict__ hx)
{
  const long nEmb = (long)SEQL * EMBD;       // 2M
  const long nWst = (long)4 * HIDD * EMBD;   // 4M
  const long nWy  = (long)NCH * HIDD;        // 512K
  const long nHx  = 2 * 256 * 32;            // [2][256][32] dwords = 64 KB
  const long total = nEmb + nWst + nWy + nHx;
  long stride = (long)gridDim.x * blockDim.x;
  for (long i = (long)blockIdx.x * blockDim.x + threadIdx.x; i < total; i += stride) {
    if (i < nEmb) {
      long t = i >> 9, e = i & 511;
      emb16[i] = (_Float16)emb[(long)seq[t] * EMBD + e];
    } else if (i < nEmb + nWst) {
      long j = i - nEmb;
      long row = j >> 9, k = j & 511;
      long r = row >> 11, jr = row & 2047;
      const float* W = (r == 0) ? Wf : (r == 1) ? Wi : (r == 2) ? Wo : Wc;
      Wst16[j] = (_Float16)W[jr * WCOL + k];
    } else if (i < nEmb + nWst + nWy) {
      long j = i - nEmb - nWst;
      Wy16[j] = (_Float16)Wy[j];             // Wy is row-major 256x2048, 1:1 copy
    } else {
      hx[i - nEmb - nWst - nWy] = 0u;
    }
  }
}

// ---------------------------------------------------------------------------
// gemm_bt: C[M][N] = A[M][K] * B[N][K]^T   (both K-contiguous f16, MFMA 16x16x32)
// MODE 0: store f16 to C16 (ldc=N).  MODE 1: store f32 + bias to Cf (ldc=N).
// 128x128 tile, BK=32, 256 threads (4 waves as 2x2 of 64x64).
// ---------------------------------------------------------------------------
template<int K, int MODE>
__global__ __launch_bounds__(256) void gemm_bt(const _Float16* __restrict__ A,
                                               const _Float16* __restrict__ B,
                                               _Float16* __restrict__ C16,
                                               float* __restrict__ Cf,
                                               const float* __restrict__ bias, int N)
{
  __shared__ _Float16 At[128 * 32];
  __shared__ _Float16 Bt[128 * 32];
  const int tid = threadIdx.x;
  const int w = tid >> 6, lane = tid & 63;
  const int wm = w >> 1, wn = w & 1;
  const int lr = lane & 15, kg = lane >> 4;
  const long tm = (long)blockIdx.y * 128;
  const long tn = (long)blockIdx.x * 128;

  float4_t acc[4][4];
#pragma unroll
  for (int a = 0; a < 4; a++)
#pragma unroll
    for (int b = 0; b < 4; b++) acc[a][b] = (float4_t)0.f;

  for (int kt = 0; kt < K; kt += 32) {
    __syncthreads();
#pragma unroll
    for (int s = 0; s < 2; s++) {
      int l = s * 256 + tid;
      int row = l >> 2, ks = (l & 3) * 8;
      *(uint4*)&At[row * 32 + ks] = *(const uint4*)&A[(tm + row) * (long)K + kt + ks];
      *(uint4*)&Bt[row * 32 + ks] = *(const uint4*)&B[(tn + row) * (long)K + kt + ks];
    }
    __syncthreads();
    half8_t af[4], bf[4];
#pragma unroll
    for (int mi = 0; mi < 4; mi++) af[mi] = *(const half8_t*)&At[(wm * 64 + mi * 16 + lr) * 32 + kg * 8];
#pragma unroll
    for (int ni = 0; ni < 4; ni++) bf[ni] = *(const half8_t*)&Bt[(wn * 64 + ni * 16 + lr) * 32 + kg * 8];
#pragma unroll
    for (int mi = 0; mi < 4; mi++)
#pragma unroll
      for (int ni = 0; ni < 4; ni++)
        acc[mi][ni] = __builtin_amdgcn_mfma_f32_16x16x32_f16(af[mi], bf[ni], acc[mi][ni], 0, 0, 0);
  }

#pragma unroll
  for (int mi = 0; mi < 4; mi++)
#pragma unroll
    for (int ni = 0; ni < 4; ni++)
#pragma unroll
      for (int i = 0; i < 4; i++) {
        long gm = tm + wm * 64 + mi * 16 + kg * 4 + i;
        long gn = tn + wn * 64 + ni * 16 + lr;
        float v = acc[mi][ni][i];
        if (MODE == 0) C16[gm * (long)N + gn] = (_Float16)v;
        else           Cf[gm * (long)N + gn] = v + bias[gn];
      }
}

// ---------------------------------------------------------------------------
// lstm_seq: persistent scan. 256 WGs x 512 threads. WG g owns hidden units
// g*8..g*8+7 (all 4 gates = 32 rows of stacked Whh, f16 in VGPRs: 64 regs/lane).
// Wave layout: wave w has rows 4w..4w+3; 16 lanes per row (hsub=lane&15).
// Lane's k slice: k = it*64 + hsub*4 + {0..3}, it = 0..31.
//
// h exchange (R3): per-producer 128 B record line per parity:
//   rec[parity][g] = 8 tagged dwords: (f16 h_k | (t+1)<<16), k = 0..7; 96 B pad.
// Word-embedded tags give data+tag atomicity per dword — NO fences anywhere
// (R2's release fence forced an L2 writeback per step per WG: 3x regression).
// Single-producer lines: at most one remote invalidation per line per step
// (R1 had 4 producer WGs sharing each line -> ~4x invalidate/refetch churn).
// Consumer: threads 0..255 each own one record line; 8 relaxed loads per poll
// round, s_sleep(1) backoff in the miss path only.
// ---------------------------------------------------------------------------
__global__ __launch_bounds__(512) void lstm_seq(
    const _Float16* __restrict__ xq,   // [SEQ][4*HID] gate-major
    const float* __restrict__ Wf, const float* __restrict__ Wi,
    const float* __restrict__ Wo, const float* __restrict__ Wc,
    const float* __restrict__ bfp, const float* __restrict__ bip,
    const float* __restrict__ bop, const float* __restrict__ bcp,
    unsigned* __restrict__ hx,         // [2][256][32] dwords (128B records)
    _Float16* __restrict__ H16,        // [SEQ][HID]
    float* __restrict__ out)
{
  __shared__ unsigned hbuf[HIDD / 2];  // f16 pairs of h_{t-1}
  __shared__ float gl[32];             // activated gates for this WG

  const int tid  = threadIdx.x;
  const int wave = tid >> 6, lane = tid & 63;
  const int rw   = lane >> 4, hsub = lane & 15;
  const int row_local = wave * 4 + rw;       // 0..31
  const int r  = row_local >> 3;             // gate: 0=f 1=i 2=o 3=c
  const int jj = row_local & 7;
  const int g  = blockIdx.x;
  const int jg = g * 8 + jj;

  const float* Wsel = (r == 0) ? Wf : (r == 1) ? Wi : (r == 2) ? Wo : Wc;
  const float* bsel = (r == 0) ? bfp : (r == 1) ? bip : (r == 2) ? bop : bcp;
  const float* wrow = Wsel + (long)jg * WCOL + EMBD;

  uint2 wreg[32];
#pragma unroll
  for (int it = 0; it < 32; ++it) {
    const float4 wv = *(const float4*)(wrow + it * 64 + hsub * 4);
    half2_t lo = { (_Float16)wv.x, (_Float16)wv.y };
    half2_t hi = { (_Float16)wv.z, (_Float16)wv.w };
    wreg[it].x = __builtin_bit_cast(unsigned, lo);
    wreg[it].y = __builtin_bit_cast(unsigned, hi);
  }
  const float bias = (hsub == 0) ? bsel[jg] : 0.f;

  float c = 0.f;   // cell state lives in wave-0 lanes 0..7

  for (int t = 0; t < SEQL; ++t) {
    // x prefetch (leaders only) — independent of h, issues before the poll
    float xv = 0.f;
    if (hsub == 0) xv = (float)xq[(long)t * 8192 + r * HIDD + g * 8 + jj];

    if (t == 0) {
      if (tid < 256) {
        hbuf[tid * 4 + 0] = 0u; hbuf[tid * 4 + 1] = 0u;
        hbuf[tid * 4 + 2] = 0u; hbuf[tid * 4 + 3] = 0u;   // h_{-1} = 0
      }
    } else if (tid < 256) {
      unsigned* rec = hx + (long)(t & 1) * 8192 + tid * 32;
      const unsigned tg16 = (unsigned)t << 16;
      unsigned d0, d1, d2, d3, d4, d5, d6, d7;
      int guard = 0;
      for (;;) {
        d0 = __hip_atomic_load(rec + 0, __ATOMIC_RELAXED, __HIP_MEMORY_SCOPE_AGENT);
        d1 = __hip_atomic_load(rec + 1, __ATOMIC_RELAXED, __HIP_MEMORY_SCOPE_AGENT);
        d2 = __hip_atomic_load(rec + 2, __ATOMIC_RELAXED, __HIP_MEMORY_SCOPE_AGENT);
        d3 = __hip_atomic_load(rec + 3, __ATOMIC_RELAXED, __HIP_MEMORY_SCOPE_AGENT);
        d4 = __hip_atomic_load(rec + 4, __ATOMIC_RELAXED, __HIP_MEMORY_SCOPE_AGENT);
        d5 = __hip_atomic_load(rec + 5, __ATOMIC_RELAXED, __HIP_MEMORY_SCOPE_AGENT);
        d6 = __hip_atomic_load(rec + 6, __ATOMIC_RELAXED, __HIP_MEMORY_SCOPE_AGENT);
        d7 = __hip_atomic_load(rec + 7, __ATOMIC_RELAXED, __HIP_MEMORY_SCOPE_AGENT);
        const unsigned m = (d0 & 0xffff0000u) ^ (d1 & 0xffff0000u) ? 1u : 0u;
        if (((d0 & 0xffff0000u) == tg16) & ((d1 & 0xffff0000u) == tg16) &
            ((d2 & 0xffff0000u) == tg16) & ((d3 & 0xffff0000u) == tg16) &
            ((d4 & 0xffff0000u) == tg16) & ((d5 & 0xffff0000u) == tg16) &
            ((d6 & 0xffff0000u) == tg16) & ((d7 & 0xffff0000u) == tg16) & !m) break;
        __builtin_amdgcn_s_sleep(1);
        if (++guard > (1 << 20)) break;   // emergency escape (never in normal flow)
      }
      hbuf[tid * 4 + 0] = (d0 & 0xffffu) | (d1 << 16);
      hbuf[tid * 4 + 1] = (d2 & 0xffffu) | (d3 << 16);
      hbuf[tid * 4 + 2] = (d4 & 0xffffu) | (d5 << 16);
      hbuf[tid * 4 + 3] = (d6 & 0xffffu) | (d7 << 16);
    }
    __syncthreads();

    // matvec: row dot h over this lane's k slice
    float a0 = 0.f, a1 = 0.f, a2 = 0.f, a3 = 0.f;
#pragma unroll
    for (int it = 0; it < 32; ++it) {
      const uint2 hv = *(const uint2*)&hbuf[it * 32 + hsub * 2];
      if (it & 1) { a2 = fdot2u(wreg[it].x, hv.x, a2); a3 = fdot2u(wreg[it].y, hv.y, a3); }
      else        { a0 = fdot2u(wreg[it].x, hv.x, a0); a1 = fdot2u(wreg[it].y, hv.y, a1); }
    }
    float s = (a0 + a1) + (a2 + a3);
    s += __shfl_xor(s, 1, 64);
    s += __shfl_xor(s, 2, 64);
    s += __shfl_xor(s, 4, 64);
    s += __shfl_xor(s, 8, 64);

    if (hsub == 0) {
      const float pre = s + xv + bias;
      gl[row_local] = (r == 3) ? tanh_f(pre) : sigm_f(pre);
    }
    __syncthreads();

    if (tid < 8) {
      const float f  = gl[tid];
      const float ii = gl[8 + tid];
      const float o  = gl[16 + tid];
      const float cg = gl[24 + tid];
      c = f * c + ii * cg;
      const float h = o * tanh_f(c);
      const _Float16 hh = (_Float16)h;
      // publish FIRST (critical path): tagged dword, relaxed, own record line
      const unsigned pk = (unsigned)__builtin_bit_cast(unsigned short, hh)
                        | ((unsigned)(t + 1) << 16);
      __hip_atomic_store(hx + (long)((t + 1) & 1) * 8192 + g * 32 + tid, pk,
                         __ATOMIC_RELAXED, __HIP_MEMORY_SCOPE_AGENT);
      H16[(long)t * HIDD + g * 8 + tid] = hh;
      if (t == SEQL - 1) {
        out[(long)SEQL * NCH + g * 8 + tid] = h;                 // final h
        out[(long)SEQL * NCH + HIDD + g * 8 + tid] = c;          // final c
      }
    }
  }
}

// ---------------------------------------------------------------------------
extern "C" void kernel_launch(void* const* d_in, const int* in_sizes, int n_in,
                              void* d_out, int out_size, void* d_ws, size_t ws_size,
                              hipStream_t stream) {
  const int*   seq = (const int*)d_in[0];
  const float* emb = (const float*)d_in[1];
  const float* Wf  = (const float*)d_in[2];
  const float* bf_ = (const float*)d_in[3];
  const float* Wi  = (const float*)d_in[4];
  const float* bi_ = (const float*)d_in[5];
  const float* Wo  = (const float*)d_in[6];
  const float* bo_ = (const float*)d_in[7];
  const float* Wc  = (const float*)d_in[8];
  const float* bc_ = (const float*)d_in[9];
  const float* Wy  = (const float*)d_in[10];
  const float* by  = (const float*)d_in[11];
  float* out = (float*)d_out;

  char* ws = (char*)d_ws;
  _Float16* xq     = (_Float16*)(ws);                          // 64 MB: [4096][8192]
  _Float16* emb16  = (_Float16*)(ws + (64ll << 20));           //  4 MB: [4096][512]
  _Float16* Wst16  = (_Float16*)(ws + (68ll << 20));           //  8 MB: [8192][512]
  _Float16* Wy16   = (_Float16*)(ws + (76ll << 20));           //  1 MB: [256][2048]
  _Float16* H16    = (_Float16*)(ws + (77ll << 20));           // 16 MB: [4096][2048]
  unsigned* hx     = (unsigned*)(ws + (93ll << 20));           // 64 KB: [2][256][32] dwords

  prep_kernel<<<2048, 256, 0, stream>>>(seq, emb, Wf, Wi, Wo, Wc, Wy,
                                        emb16, Wst16, Wy16, hx);

  dim3 g1(8192 / 128, 4096 / 128);   // N tiles x M tiles
  gemm_bt<EMBD, 0><<<g1, 256, 0, stream>>>(emb16, Wst16, xq, nullptr, nullptr, 8192);

  lstm_seq<<<256, 512, 0, stream>>>(xq, Wf, Wi, Wo, Wc, bf_, bi_, bo_, bc_,
                                    hx, H16, out);

  dim3 g2(NCH / 128, 4096 / 128);
  gemm_bt<HIDD, 1><<<g2, 256, 0, stream>>>(H16, Wy16, nullptr, out, by, NCH);
}

// Round 4
// 8390.560 us; speedup vs baseline: 3.5080x; 1.8455x over previous
//
#include <hip/hip_runtime.h>
#include <hip/hip_fp16.h>

#define SEQL 4096
#define EMBD 512
#define HIDD 2048
#define NCH  256
#define WCOL 2560   // EMB + HID

typedef _Float16 half8_t  __attribute__((ext_vector_type(8)));
typedef _Float16 half2_t  __attribute__((ext_vector_type(2)));
typedef float    float4_t __attribute__((ext_vector_type(4)));
typedef unsigned uint4_t  __attribute__((ext_vector_type(4)));
typedef unsigned uint2_t  __attribute__((ext_vector_type(2)));

#if __has_builtin(__builtin_amdgcn_fdot2)
__device__ __forceinline__ float fdot2u(unsigned a, unsigned b, float c) {
  return __builtin_amdgcn_fdot2(__builtin_bit_cast(half2_t, a),
                                __builtin_bit_cast(half2_t, b), c, false);
}
#else
__device__ __forceinline__ float fdot2u(unsigned a, unsigned b, float c) {
  half2_t ha = __builtin_bit_cast(half2_t, a), hb = __builtin_bit_cast(half2_t, b);
  return c + (float)ha.x * (float)hb.x + (float)ha.y * (float)hb.y;
}
#endif

__device__ __forceinline__ float sigm_f(float x)  { return 1.f / (1.f + __expf(-x)); }
__device__ __forceinline__ float tanh_f(float x)  { return 1.f - 2.f / (__expf(2.f * x) + 1.f); }

// 16B poll load: bypasses L1/L2 (sc1) so remote producers' tagged dwords are
// visible; volatile asm so it re-issues every round. Tags are embedded per
// dword -> per-dword atomicity is all we need, no fences anywhere.
__device__ __forceinline__ uint4_t poll_ld(const unsigned* p) {
  uint4_t r;
  asm volatile("global_load_dwordx4 %0, %1, off sc1\n\ts_waitcnt vmcnt(0)"
               : "=v"(r) : "v"(p) : "memory");
  return r;
}

// ---------------------------------------------------------------------------
// prep: f32->f16 conversions (emb gather, stacked recurrent-GEMM B, Wy) and
//       zeroing of the packed h-exchange buffer (must re-run every launch:
//       stale tags from a previous replay would falsely match).
// ---------------------------------------------------------------------------
__global__ void prep_kernel(const int* __restrict__ seq, const float* __restrict__ emb,
                            const float* __restrict__ Wf, const float* __restrict__ Wi,
                            const float* __restrict__ Wo, const float* __restrict__ Wc,
                            const float* __restrict__ Wy,
                            _Float16* __restrict__ emb16, _Float16* __restrict__ Wst16,
                            _Float16* __restrict__ Wy16, unsigned* __restrict__ hx)
{
  const long nEmb = (long)SEQL * EMBD;       // 2M
  const long nWst = (long)4 * HIDD * EMBD;   // 4M
  const long nWy  = (long)NCH * HIDD;        // 512K
  const long nHx  = 2 * HIDD;                // [2][2048] tagged dwords = 16 KB
  const long total = nEmb + nWst + nWy + nHx;
  long stride = (long)gridDim.x * blockDim.x;
  for (long i = (long)blockIdx.x * blockDim.x + threadIdx.x; i < total; i += stride) {
    if (i < nEmb) {
      long t = i >> 9, e = i & 511;
      emb16[i] = (_Float16)emb[(long)seq[t] * EMBD + e];
    } else if (i < nEmb + nWst) {
      long j = i - nEmb;
      long row = j >> 9, k = j & 511;
      long r = row >> 11, jr = row & 2047;
      const float* W = (r == 0) ? Wf : (r == 1) ? Wi : (r == 2) ? Wo : Wc;
      Wst16[j] = (_Float16)W[jr * WCOL + k];
    } else if (i < nEmb + nWst + nWy) {
      long j = i - nEmb - nWst;
      Wy16[j] = (_Float16)Wy[j];             // Wy is row-major 256x2048, 1:1 copy
    } else {
      hx[i - nEmb - nWst - nWy] = 0u;
    }
  }
}

// ---------------------------------------------------------------------------
// gemm_bt: C[M][N] = A[M][K] * B[N][K]^T   (both K-contiguous f16, MFMA 16x16x32)
// MODE 0: store f16 to C16 (ldc=N).  MODE 1: store f32 + bias to Cf (ldc=N).
// 128x128 tile, BK=32, 256 threads (4 waves as 2x2 of 64x64).
// ---------------------------------------------------------------------------
template<int K, int MODE>
__global__ __launch_bounds__(256) void gemm_bt(const _Float16* __restrict__ A,
                                               const _Float16* __restrict__ B,
                                               _Float16* __restrict__ C16,
                                               float* __restrict__ Cf,
                                               const float* __restrict__ bias, int N)
{
  __shared__ _Float16 At[128 * 32];
  __shared__ _Float16 Bt[128 * 32];
  const int tid = threadIdx.x;
  const int w = tid >> 6, lane = tid & 63;
  const int wm = w >> 1, wn = w & 1;
  const int lr = lane & 15, kg = lane >> 4;
  const long tm = (long)blockIdx.y * 128;
  const long tn = (long)blockIdx.x * 128;

  float4_t acc[4][4];
#pragma unroll
  for (int a = 0; a < 4; a++)
#pragma unroll
    for (int b = 0; b < 4; b++) acc[a][b] = (float4_t)0.f;

  for (int kt = 0; kt < K; kt += 32) {
    __syncthreads();
#pragma unroll
    for (int s = 0; s < 2; s++) {
      int l = s * 256 + tid;
      int row = l >> 2, ks = (l & 3) * 8;
      *(uint4*)&At[row * 32 + ks] = *(const uint4*)&A[(tm + row) * (long)K + kt + ks];
      *(uint4*)&Bt[row * 32 + ks] = *(const uint4*)&B[(tn + row) * (long)K + kt + ks];
    }
    __syncthreads();
    half8_t af[4], bf[4];
#pragma unroll
    for (int mi = 0; mi < 4; mi++) af[mi] = *(const half8_t*)&At[(wm * 64 + mi * 16 + lr) * 32 + kg * 8];
#pragma unroll
    for (int ni = 0; ni < 4; ni++) bf[ni] = *(const half8_t*)&Bt[(wn * 64 + ni * 16 + lr) * 32 + kg * 8];
#pragma unroll
    for (int mi = 0; mi < 4; mi++)
#pragma unroll
      for (int ni = 0; ni < 4; ni++)
        acc[mi][ni] = __builtin_amdgcn_mfma_f32_16x16x32_f16(af[mi], bf[ni], acc[mi][ni], 0, 0, 0);
  }

#pragma unroll
  for (int mi = 0; mi < 4; mi++)
#pragma unroll
    for (int ni = 0; ni < 4; ni++)
#pragma unroll
      for (int i = 0; i < 4; i++) {
        long gm = tm + wm * 64 + mi * 16 + kg * 4 + i;
        long gn = tn + wn * 64 + ni * 16 + lr;
        float v = acc[mi][ni][i];
        if (MODE == 0) C16[gm * (long)N + gn] = (_Float16)v;
        else           Cf[gm * (long)N + gn] = v + bias[gn];
      }
}

// ---------------------------------------------------------------------------
// lstm_seq (R4): persistent scan. 256 WGs x 512 threads (8 waves).
// Wave w of WG g owns hidden unit j = g*8 + w, ALL FOUR gates:
//   rw = lane>>4 selects gate (0=f 1=i 2=o 3=c), hsub = lane&15 is the k-slice.
// Gate reduce + cell update + publish are wave-local (shuffles only);
// ONE __syncthreads per step (after the LDS h fill, double-buffered).
//
// h exchange: packed hx[2][2048] tagged dwords (f16 h | t+1 <<16), written
// with relaxed agent atomics (sc1 write-through). Consumers: 512 threads each
// poll one 16B slice via global_load_dwordx4 sc1 (4 embedded tags per load).
// ---------------------------------------------------------------------------
__global__ __launch_bounds__(512) void lstm_seq(
    const _Float16* __restrict__ xq,   // [SEQ][4*HID] gate-major
    const float* __restrict__ Wf, const float* __restrict__ Wi,
    const float* __restrict__ Wo, const float* __restrict__ Wc,
    const float* __restrict__ bfp, const float* __restrict__ bip,
    const float* __restrict__ bop, const float* __restrict__ bcp,
    unsigned* __restrict__ hx,         // [2][2048] tagged dwords
    _Float16* __restrict__ H16,        // [SEQ][HID]
    float* __restrict__ out)
{
  __shared__ uint2_t hbuf2[2][512];    // packed f16 pairs of h, double-buffered

  const int tid  = threadIdx.x;
  const int w    = tid >> 6, lane = tid & 63;
  const int rw   = lane >> 4, hsub = lane & 15;   // gate, k-subslice
  const int g    = blockIdx.x;
  const int jg   = g * 8 + w;                     // this wave's hidden unit

  const float* Wsel = (rw == 0) ? Wf : (rw == 1) ? Wi : (rw == 2) ? Wo : Wc;
  const float* bsel = (rw == 0) ? bfp : (rw == 1) ? bip : (rw == 2) ? bop : bcp;
  const float* wrow = Wsel + (long)jg * WCOL + EMBD;

  uint2 wreg[32];
#pragma unroll
  for (int it = 0; it < 32; ++it) {
    const float4 wv = *(const float4*)(wrow + it * 64 + hsub * 4);
    half2_t lo = { (_Float16)wv.x, (_Float16)wv.y };
    half2_t hi = { (_Float16)wv.z, (_Float16)wv.w };
    wreg[it].x = __builtin_bit_cast(unsigned, lo);
    wreg[it].y = __builtin_bit_cast(unsigned, hi);
  }
  const float bias = (hsub == 0) ? bsel[jg] : 0.f;

  float c = 0.f;   // cell state lives in lane 0 of each wave

  for (int t = 0; t < SEQL; ++t) {
    const int par = t & 1;
    // x prefetch (one lane per gate) — independent of h, issues before poll
    float xv = 0.f;
    if (hsub == 0) xv = (float)xq[(long)t * 8192 + rw * HIDD + jg];

    if (t == 0) {
      uint2_t z; z.x = 0u; z.y = 0u;
      hbuf2[0][tid] = z;                           // h_{-1} = 0
    } else {
      const unsigned* slice = hx + (long)par * HIDD + tid * 4;
      const unsigned tg = (unsigned)t;
      uint4_t v;
      int guard = 0;
      for (;;) {
        v = poll_ld(slice);
        if (((v.x >> 16) == tg) & ((v.y >> 16) == tg) &
            ((v.z >> 16) == tg) & ((v.w >> 16) == tg)) break;
        if (++guard > (1 << 22)) break;   // emergency escape (never in normal flow)
      }
      uint2_t p;
      p.x = (v.x & 0xffffu) | (v.y << 16);
      p.y = (v.z & 0xffffu) | (v.w << 16);
      hbuf2[par][tid] = p;
    }
    __syncthreads();

    // matvec: gate-row (rw) of unit jg dot h, over this lane's k slice
    float a0 = 0.f, a1 = 0.f, a2 = 0.f, a3 = 0.f;
#pragma unroll
    for (int it = 0; it < 32; ++it) {
      const uint2_t hv = hbuf2[par][it * 16 + hsub];
      if (it & 1) { a2 = fdot2u(wreg[it].x, hv.x, a2); a3 = fdot2u(wreg[it].y, hv.y, a3); }
      else        { a0 = fdot2u(wreg[it].x, hv.x, a0); a1 = fdot2u(wreg[it].y, hv.y, a1); }
    }
    float s = (a0 + a1) + (a2 + a3);
    s += __shfl_xor(s, 1, 64);
    s += __shfl_xor(s, 2, 64);
    s += __shfl_xor(s, 4, 64);
    s += __shfl_xor(s, 8, 64);

    // activation on the 4 leader lanes (hsub==0), then wave-local gather
    float act = 0.f;
    if (hsub == 0) {
      const float pre = s + xv + bias;
      act = (rw == 3) ? tanh_f(pre) : sigm_f(pre);
    }
    const float af = __shfl(act, 0,  64);
    const float ai = __shfl(act, 16, 64);
    const float ao = __shfl(act, 32, 64);
    const float ac = __shfl(act, 48, 64);

    if (lane == 0) {
      c = af * c + ai * ac;
      const float h = ao * tanh_f(c);
      const _Float16 hh = (_Float16)h;
      // publish FIRST (critical path): tagged dword, relaxed agent atomic
      const unsigned pk = (unsigned)__builtin_bit_cast(unsigned short, hh)
                        | ((unsigned)(t + 1) << 16);
      __hip_atomic_store(hx + (long)((t + 1) & 1) * HIDD + jg, pk,
                         __ATOMIC_RELAXED, __HIP_MEMORY_SCOPE_AGENT);
      H16[(long)t * HIDD + jg] = hh;
      if (t == SEQL - 1) {
        out[(long)SEQL * NCH + jg] = h;                 // final h
        out[(long)SEQL * NCH + HIDD + jg] = c;          // final c
      }
    }
  }
}

// ---------------------------------------------------------------------------
extern "C" void kernel_launch(void* const* d_in, const int* in_sizes, int n_in,
                              void* d_out, int out_size, void* d_ws, size_t ws_size,
                              hipStream_t stream) {
  const int*   seq = (const int*)d_in[0];
  const float* emb = (const float*)d_in[1];
  const float* Wf  = (const float*)d_in[2];
  const float* bf_ = (const float*)d_in[3];
  const float* Wi  = (const float*)d_in[4];
  const float* bi_ = (const float*)d_in[5];
  const float* Wo  = (const float*)d_in[6];
  const float* bo_ = (const float*)d_in[7];
  const float* Wc  = (const float*)d_in[8];
  const float* bc_ = (const float*)d_in[9];
  const float* Wy  = (const float*)d_in[10];
  const float* by  = (const float*)d_in[11];
  float* out = (float*)d_out;

  char* ws = (char*)d_ws;
  _Float16* xq     = (_Float16*)(ws);                          // 64 MB: [4096][8192]
  _Float16* emb16  = (_Float16*)(ws + (64ll << 20));           //  4 MB: [4096][512]
  _Float16* Wst16  = (_Float16*)(ws + (68ll << 20));           //  8 MB: [8192][512]
  _Float16* Wy16   = (_Float16*)(ws + (76ll << 20));           //  1 MB: [256][2048]
  _Float16* H16    = (_Float16*)(ws + (77ll << 20));           // 16 MB: [4096][2048]
  unsigned* hx     = (unsigned*)(ws + (93ll << 20));           // 16 KB: [2][2048] dwords

  prep_kernel<<<2048, 256, 0, stream>>>(seq, emb, Wf, Wi, Wo, Wc, Wy,
                                        emb16, Wst16, Wy16, hx);

  dim3 g1(8192 / 128, 4096 / 128);   // N tiles x M tiles
  gemm_bt<EMBD, 0><<<g1, 256, 0, stream>>>(emb16, Wst16, xq, nullptr, nullptr, 8192);

  lstm_seq<<<256, 512, 0, stream>>>(xq, Wf, Wi, Wo, Wc, bf_, bi_, bo_, bc_,
                                    hx, H16, out);

  dim3 g2(NCH / 128, 4096 / 128);
  gemm_bt<HIDD, 1><<<g2, 256, 0, stream>>>(H16, Wy16, nullptr, out, by, NCH);
}